// Round 1
// baseline (413.085 us; speedup 1.0000x reference)
//
#include <hip/hip_runtime.h>
#include <hip/hip_bf16.h>
#include <stdint.h>
#include <stddef.h>

// MultiHA: y@Wq^T -> q; x@Wk^T -> k; x@Wv^T -> v; causal softmax attn; @Wp^T + bp
// B=4 S=2048 D=1024 NH=16 HS=64. All GEMM/attn compute in bf16 MFMA, f32 accum.

typedef __attribute__((ext_vector_type(4))) float f32x4;
typedef __attribute__((ext_vector_type(8))) short s16x8;
typedef __attribute__((ext_vector_type(4))) float float4v;

#define DEV __device__ __forceinline__

constexpr int Bsz = 4, Sseq = 2048, Dm = 1024, NHn = 16, HSn = 64;
constexpr int BHn = Bsz * NHn; // 64
// fold 1/sqrt(HS) * log2(e) into Wq so attention softmax runs in exp2 domain
constexpr float QSCALE = 0.125f * 1.4426950408889634f;

// ---- workspace layout (bytes) ----
constexpr size_t SZ_BF_XY = (size_t)Bsz * Sseq * Dm * 2;  // 16 MiB
constexpr size_t SZ_W     = (size_t)Dm * Dm * 2;          // 2 MiB
constexpr size_t OFF_XBF  = 0;
constexpr size_t OFF_YBF  = OFF_XBF + SZ_BF_XY;
constexpr size_t OFF_WQ   = OFF_YBF + SZ_BF_XY;
constexpr size_t OFF_WK   = OFF_WQ + SZ_W;
constexpr size_t OFF_WV   = OFF_WK + SZ_W;
constexpr size_t OFF_WP   = OFF_WV + SZ_W;
constexpr size_t OFF_QWS  = OFF_WP + SZ_W;   // [BH][S][64] bf16
constexpr size_t OFF_KWS  = OFF_QWS + SZ_BF_XY;
constexpr size_t OFF_VTWS = OFF_KWS + SZ_BF_XY; // [BH][64][S] bf16 (V transposed)
constexpr size_t OFF_OWS  = OFF_VTWS + SZ_BF_XY; // attn out [B][S][D] bf16
constexpr size_t OFF_FLAG = OFF_OWS + SZ_BF_XY;

DEV unsigned short f2bf(float f) {
  union { float f; unsigned int u; } v; v.f = f;
  unsigned int r = (v.u + 0x7FFFu + ((v.u >> 16) & 1u)) >> 16;
  return (unsigned short)r;
}

DEV void gll16(const void* g, void* l) {
  __builtin_amdgcn_global_load_lds((const __attribute__((address_space(1))) unsigned int*)g,
                                   (__attribute__((address_space(3))) unsigned int*)l, 16, 0, 0);
}

// ---------------- convert fp32 -> bf16 (x8 per thread) ----------------
__global__ void cvt_kernel(const float* __restrict__ src, unsigned short* __restrict__ dst,
                           int n8, float scale) {
  int i = blockIdx.x * blockDim.x + threadIdx.x;
  if (i >= n8) return;
  const float4v* s = (const float4v*)src + (size_t)i * 2;
  float4v a = s[0], b = s[1];
  s16x8 o;
  o[0] = (short)f2bf(a[0] * scale); o[1] = (short)f2bf(a[1] * scale);
  o[2] = (short)f2bf(a[2] * scale); o[3] = (short)f2bf(a[3] * scale);
  o[4] = (short)f2bf(b[0] * scale); o[5] = (short)f2bf(b[1] * scale);
  o[6] = (short)f2bf(b[2] * scale); o[7] = (short)f2bf(b[3] * scale);
  *(s16x8*)(dst + (size_t)i * 8) = o;
}

// ---------------- mask triviality flag ----------------
__global__ void init_flag(int* f) { f[0] = 1; }
__global__ void check_mask(const int* __restrict__ p, int n, int* __restrict__ f) {
  int bad = 0;
  for (int i = blockIdx.x * blockDim.x + threadIdx.x; i < n; i += gridDim.x * blockDim.x)
    bad |= (p[i] == 0);
  if (bad) atomicAnd(f, 0);
}

// ---------------- 128x128 bf16 GEMM, C[m][n] = sum_k A[m][k] * W[n][k] ----------------
// V=0: Q out bf16 [B,NH,S,HS]   V=1: K out, same layout
// V=2: Vt out bf16 [B,NH,HS,S] (LDS-transposed epilogue)
// V=3: fp32 out [M][1024] + bias
template <int V>
__global__ __launch_bounds__(256) void gemm_k(const unsigned short* __restrict__ A,
                                              const unsigned short* __restrict__ W,
                                              unsigned short* __restrict__ outb,
                                              float* __restrict__ outf,
                                              const float* __restrict__ bias) {
  constexpr int K = 1024;
  __shared__ unsigned short sm[17408]; // lA(4096) + lB(4096); V2 transpose uses 128*136
  unsigned short* lA = sm;
  unsigned short* lB = sm + 4096;
  const int tid = threadIdx.x;
  const int w = tid >> 6, lane = tid & 63, lo = lane & 15, hi = lane >> 4;
  const int wm = w >> 1, wn = w & 1;
  const int m0 = blockIdx.x * 128, n0 = blockIdx.y * 128;
  f32x4 acc[4][4] = {};

  for (int k0 = 0; k0 < K; k0 += 32) {
#pragma unroll
    for (int h = 0; h < 2; ++h) {
      int c = w * 64 + h * 256 + lane;
      gll16(A + (size_t)(m0 + (c >> 2)) * K + k0 + (c & 3) * 8, lA + (size_t)(w * 64 + h * 256) * 8);
      gll16(W + (size_t)(n0 + (c >> 2)) * K + k0 + (c & 3) * 8, lB + (size_t)(w * 64 + h * 256) * 8);
    }
    __syncthreads();
    s16x8 af[4], bfr[4];
#pragma unroll
    for (int mi = 0; mi < 4; ++mi) af[mi] = *(const s16x8*)&lA[(wm * 64 + mi * 16 + lo) * 32 + hi * 8];
#pragma unroll
    for (int ni = 0; ni < 4; ++ni) bfr[ni] = *(const s16x8*)&lB[(wn * 64 + ni * 16 + lo) * 32 + hi * 8];
#pragma unroll
    for (int mi = 0; mi < 4; ++mi)
#pragma unroll
      for (int ni = 0; ni < 4; ++ni)
        acc[mi][ni] = __builtin_amdgcn_mfma_f32_16x16x32_bf16(af[mi], bfr[ni], acc[mi][ni], 0, 0, 0);
    __syncthreads();
  }

  if constexpr (V <= 1) {
#pragma unroll
    for (int mi = 0; mi < 4; ++mi)
#pragma unroll
      for (int ni = 0; ni < 4; ++ni)
#pragma unroll
        for (int j = 0; j < 4; ++j) {
          int m = m0 + wm * 64 + mi * 16 + hi * 4 + j;
          int n = n0 + wn * 64 + ni * 16 + lo;
          int b = m >> 11, s = m & 2047, hh = n >> 6, e = n & 63;
          outb[((size_t)(b * NHn + hh) * Sseq + s) * HSn + e] = f2bf(acc[mi][ni][j]);
        }
  } else if constexpr (V == 2) {
    __syncthreads();
#pragma unroll
    for (int mi = 0; mi < 4; ++mi)
#pragma unroll
      for (int ni = 0; ni < 4; ++ni)
#pragma unroll
        for (int j = 0; j < 4; ++j) {
          int ml = wm * 64 + mi * 16 + hi * 4 + j;
          int nl = wn * 64 + ni * 16 + lo;
          sm[(size_t)nl * 136 + ml] = f2bf(acc[mi][ni][j]);
        }
    __syncthreads();
    int nl = tid >> 1, half = tid & 1;
    int b = m0 >> 11, hh = (n0 + nl) >> 6, e = (n0 + nl) & 63;
    unsigned short* dst = outb + ((size_t)(b * NHn + hh) * HSn + e) * Sseq + (m0 & 2047) + half * 64;
#pragma unroll
    for (int i = 0; i < 8; ++i)
      *(s16x8*)(dst + i * 8) = *(const s16x8*)&sm[(size_t)nl * 136 + half * 64 + i * 8];
  } else {
    float bv[4];
#pragma unroll
    for (int ni = 0; ni < 4; ++ni) bv[ni] = bias[n0 + wn * 64 + ni * 16 + lo];
#pragma unroll
    for (int mi = 0; mi < 4; ++mi)
#pragma unroll
      for (int ni = 0; ni < 4; ++ni)
#pragma unroll
        for (int j = 0; j < 4; ++j) {
          int m = m0 + wm * 64 + mi * 16 + hi * 4 + j;
          int n = n0 + wn * 64 + ni * 16 + lo;
          outf[(size_t)m * 1024 + n] = acc[mi][ni][j] + bv[ni];
        }
  }
}

// ---------------- flash attention ----------------
// grid: (S/128, B*NH); 4 waves, each owns 32 q-rows. KBLK=64 staged in LDS.
// Q pre-scaled by QSCALE (in Wq), so softmax is exp2-domain.
__global__ __launch_bounds__(256) void attn_kernel(const unsigned short* __restrict__ Q,
                                                   const unsigned short* __restrict__ Kg,
                                                   const unsigned short* __restrict__ Vt,
                                                   unsigned short* __restrict__ O,
                                                   const int* __restrict__ pad,
                                                   const int* __restrict__ tmask,
                                                   const int* __restrict__ flags) {
  __shared__ unsigned short kb[64 * 72];
  __shared__ unsigned short vb[64 * 72];
  __shared__ unsigned short pb[4][32 * 72];
  __shared__ float bcast[4][32];

  const int qt = blockIdx.x, bh = blockIdx.y;
  const int b = bh >> 4, hh = bh & 15;
  const int tid = threadIdx.x, w = tid >> 6, lane = tid & 63, lo = lane & 15, hi = lane >> 4;
  const int q0 = qt * 128, qw0 = q0 + w * 32;
  const bool trivial = flags[0] != 0;

  const unsigned short* Qb = Q + (size_t)bh * Sseq * HSn;
  const unsigned short* Kb = Kg + (size_t)bh * Sseq * HSn;
  const unsigned short* Vb = Vt + (size_t)bh * HSn * Sseq;

  // Q fragments in registers (A-operand: row=lo, k=hi*8+j)
  s16x8 qf[2][2];
#pragma unroll
  for (int mq = 0; mq < 2; ++mq)
#pragma unroll
    for (int kk = 0; kk < 2; ++kk)
      qf[mq][kk] = *(const s16x8*)&Qb[(size_t)(qw0 + mq * 16 + lo) * HSn + kk * 32 + hi * 8];

  f32x4 oacc[4][2] = {};
  float mrun[2][4], lrun[2][4];
#pragma unroll
  for (int mq = 0; mq < 2; ++mq)
#pragma unroll
    for (int j = 0; j < 4; ++j) { mrun[mq][j] = -3e38f; lrun[mq][j] = 0.f; }

  const int nkt = (q0 + 128) / 64;
  for (int kt = 0; kt < nkt; ++kt) {
    const int k0 = kt * 64;
    { // cooperative stage: K rows [kpos][e], Vt rows [e][kpos]; padded stride 72
      int r = tid >> 2, qtr = tid & 3;
      const unsigned short* gk = Kb + (size_t)(k0 + r) * HSn + qtr * 16;
      *(s16x8*)&kb[r * 72 + qtr * 16] = *(const s16x8*)gk;
      *(s16x8*)&kb[r * 72 + qtr * 16 + 8] = *(const s16x8*)(gk + 8);
      const unsigned short* gv = Vb + (size_t)r * Sseq + k0 + qtr * 16;
      *(s16x8*)&vb[r * 72 + qtr * 16] = *(const s16x8*)gv;
      *(s16x8*)&vb[r * 72 + qtr * 16 + 8] = *(const s16x8*)(gv + 8);
    }
    __syncthreads();

    if (k0 <= qw0 + 31) {
      // S = Q K^T  (C-layout: row q = hi*4+j, col kpos = lo)
      f32x4 sreg[2][4];
#pragma unroll
      for (int t = 0; t < 4; ++t) {
        f32x4 s0 = {0.f, 0.f, 0.f, 0.f}, s1 = {0.f, 0.f, 0.f, 0.f};
#pragma unroll
        for (int kk = 0; kk < 2; ++kk) {
          s16x8 kfr = *(const s16x8*)&kb[(t * 16 + lo) * 72 + kk * 32 + hi * 8];
          s0 = __builtin_amdgcn_mfma_f32_16x16x32_bf16(qf[0][kk], kfr, s0, 0, 0, 0);
          s1 = __builtin_amdgcn_mfma_f32_16x16x32_bf16(qf[1][kk], kfr, s1, 0, 0, 0);
        }
        sreg[0][t] = s0; sreg[1][t] = s1;
      }
      if (k0 + 63 > qw0) { // diagonal tiles: causal mask
#pragma unroll
        for (int mq = 0; mq < 2; ++mq)
#pragma unroll
          for (int t = 0; t < 4; ++t)
#pragma unroll
            for (int j = 0; j < 4; ++j) {
              int qg = qw0 + mq * 16 + hi * 4 + j;
              int kg = k0 + t * 16 + lo;
              if (kg > qg) sreg[mq][t][j] = -3e38f;
            }
      }
      if (!trivial) { // general pad/time masks (not hit for all-ones inputs)
#pragma unroll
        for (int t = 0; t < 4; ++t) {
          int kg = k0 + t * 16 + lo;
          int pv = pad[b * Sseq + kg];
#pragma unroll
          for (int mq = 0; mq < 2; ++mq)
#pragma unroll
            for (int j = 0; j < 4; ++j) {
              int qg = qw0 + mq * 16 + hi * 4 + j;
              if (!pv || !tmask[(size_t)qg * Sseq + kg]) sreg[mq][t][j] = -3e38f;
            }
        }
      }
      // online softmax (exp2 domain), per row (mq, j)
#pragma unroll
      for (int mq = 0; mq < 2; ++mq)
#pragma unroll
        for (int j = 0; j < 4; ++j) {
          float mx = fmaxf(fmaxf(sreg[mq][0][j], sreg[mq][1][j]),
                           fmaxf(sreg[mq][2][j], sreg[mq][3][j]));
          mx = fmaxf(mx, __shfl_xor(mx, 1, 64));
          mx = fmaxf(mx, __shfl_xor(mx, 2, 64));
          mx = fmaxf(mx, __shfl_xor(mx, 4, 64));
          mx = fmaxf(mx, __shfl_xor(mx, 8, 64));
          float mnew = fmaxf(mrun[mq][j], mx);
          float al = __builtin_amdgcn_exp2f(mrun[mq][j] - mnew);
          mrun[mq][j] = mnew;
          float rs = 0.f;
#pragma unroll
          for (int t = 0; t < 4; ++t) {
            float p = __builtin_amdgcn_exp2f(sreg[mq][t][j] - mnew);
            sreg[mq][t][j] = p;
            rs += p;
          }
          rs += __shfl_xor(rs, 1, 64);
          rs += __shfl_xor(rs, 2, 64);
          rs += __shfl_xor(rs, 4, 64);
          rs += __shfl_xor(rs, 8, 64);
          lrun[mq][j] = lrun[mq][j] * al + rs;
          if (lo == 0) bcast[w][mq * 16 + hi * 4 + j] = al;
        }
      // P -> LDS bf16 [q][kpos]
#pragma unroll
      for (int mq = 0; mq < 2; ++mq)
#pragma unroll
        for (int t = 0; t < 4; ++t)
#pragma unroll
          for (int j = 0; j < 4; ++j)
            pb[w][(mq * 16 + hi * 4 + j) * 72 + t * 16 + lo] = f2bf(sreg[mq][t][j]);
      // rescale O^T accumulators (col = q = lo)
      float av0 = bcast[w][lo], av1 = bcast[w][16 + lo];
#pragma unroll
      for (int et = 0; et < 4; ++et) { oacc[et][0] *= av0; oacc[et][1] *= av1; }
      // O^T += V^T P^T
      s16x8 pf[2][2];
#pragma unroll
      for (int ql = 0; ql < 2; ++ql)
#pragma unroll
        for (int kk = 0; kk < 2; ++kk)
          pf[ql][kk] = *(const s16x8*)&pb[w][(ql * 16 + lo) * 72 + kk * 32 + hi * 8];
#pragma unroll
      for (int et = 0; et < 4; ++et)
#pragma unroll
        for (int kk = 0; kk < 2; ++kk) {
          s16x8 vfr = *(const s16x8*)&vb[(et * 16 + lo) * 72 + kk * 32 + hi * 8];
          oacc[et][0] = __builtin_amdgcn_mfma_f32_16x16x32_bf16(vfr, pf[0][kk], oacc[et][0], 0, 0, 0);
          oacc[et][1] = __builtin_amdgcn_mfma_f32_16x16x32_bf16(vfr, pf[1][kk], oacc[et][1], 0, 0, 0);
        }
    }
    __syncthreads();
  }

  // normalize by l (broadcast through LDS), write O via per-wave LDS transpose
  if (lo == 0) {
#pragma unroll
    for (int mq = 0; mq < 2; ++mq)
#pragma unroll
      for (int j = 0; j < 4; ++j) bcast[w][mq * 16 + hi * 4 + j] = lrun[mq][j];
  }
  float inv0 = 1.f / bcast[w][lo];
  float inv1 = 1.f / bcast[w][16 + lo];
#pragma unroll
  for (int et = 0; et < 4; ++et) { oacc[et][0] *= inv0; oacc[et][1] *= inv1; }
#pragma unroll
  for (int et = 0; et < 4; ++et)
#pragma unroll
    for (int ql = 0; ql < 2; ++ql)
#pragma unroll
      for (int j = 0; j < 4; ++j)
        pb[w][(ql * 16 + lo) * 72 + et * 16 + hi * 4 + j] = f2bf(oacc[et][ql][j]);
  int q = lane & 31, half = lane >> 5;
  unsigned short* dst = O + ((size_t)(b * Sseq) + qw0 + q) * Dm + hh * HSn + half * 32;
#pragma unroll
  for (int i = 0; i < 4; ++i)
    *(s16x8*)(dst + i * 8) = *(const s16x8*)&pb[w][q * 72 + half * 32 + i * 8];
}

extern "C" void kernel_launch(void* const* d_in, const int* in_sizes, int n_in,
                              void* d_out, int out_size, void* d_ws, size_t ws_size,
                              hipStream_t stream) {
  const float* x = (const float*)d_in[0];
  const float* y = (const float*)d_in[1];
  const int* pad = (const int*)d_in[2];
  const int* tmask = (const int*)d_in[3];
  const float* Wq = (const float*)d_in[4];
  const float* Wk = (const float*)d_in[5];
  const float* Wv = (const float*)d_in[6];
  const float* Wp = (const float*)d_in[7];
  const float* bp = (const float*)d_in[8];

  char* ws = (char*)d_ws;
  unsigned short* xbf = (unsigned short*)(ws + OFF_XBF);
  unsigned short* ybf = (unsigned short*)(ws + OFF_YBF);
  unsigned short* wqb = (unsigned short*)(ws + OFF_WQ);
  unsigned short* wkb = (unsigned short*)(ws + OFF_WK);
  unsigned short* wvb = (unsigned short*)(ws + OFF_WV);
  unsigned short* wpb = (unsigned short*)(ws + OFF_WP);
  unsigned short* qws = (unsigned short*)(ws + OFF_QWS);
  unsigned short* kws = (unsigned short*)(ws + OFF_KWS);
  unsigned short* vtw = (unsigned short*)(ws + OFF_VTWS);
  unsigned short* ows = (unsigned short*)(ws + OFF_OWS);
  int* flags = (int*)(ws + OFF_FLAG);

  init_flag<<<1, 1, 0, stream>>>(flags);
  check_mask<<<64, 256, 0, stream>>>(pad, Bsz * Sseq, flags);
  check_mask<<<2048, 256, 0, stream>>>(tmask, Sseq * Sseq, flags);

  cvt_kernel<<<4096, 256, 0, stream>>>(x, xbf, 1048576, 1.f);
  cvt_kernel<<<4096, 256, 0, stream>>>(y, ybf, 1048576, 1.f);
  cvt_kernel<<<512, 256, 0, stream>>>(Wq, wqb, 131072, QSCALE);
  cvt_kernel<<<512, 256, 0, stream>>>(Wk, wkb, 131072, 1.f);
  cvt_kernel<<<512, 256, 0, stream>>>(Wv, wvb, 131072, 1.f);
  cvt_kernel<<<512, 256, 0, stream>>>(Wp, wpb, 131072, 1.f);

  dim3 gg(64, 8);
  gemm_k<0><<<gg, 256, 0, stream>>>(ybf, wqb, qws, nullptr, nullptr);
  gemm_k<1><<<gg, 256, 0, stream>>>(xbf, wkb, kws, nullptr, nullptr);
  gemm_k<2><<<gg, 256, 0, stream>>>(xbf, wvb, vtw, nullptr, nullptr);

  attn_kernel<<<dim3(16, 64), 256, 0, stream>>>(qws, kws, vtw, ows, pad, tmask, flags);

  gemm_k<3><<<gg, 256, 0, stream>>>(ows, wpb, nullptr, (float*)d_out, bp);
}

// Round 3
// 286.892 us; speedup vs baseline: 1.4399x; 1.4399x over previous
//
#include <hip/hip_runtime.h>
#include <hip/hip_bf16.h>
#include <stdint.h>
#include <stddef.h>

// MultiHA: y@Wq^T -> q; x@Wk^T -> k; x@Wv^T -> v; causal softmax attn; @Wp^T + bp
// B=4 S=2048 D=1024 NH=16 HS=64. All GEMM/attn compute in bf16 MFMA, f32 accum.

typedef __attribute__((ext_vector_type(4))) float f32x4;
typedef __attribute__((ext_vector_type(8))) short s16x8;
typedef __attribute__((ext_vector_type(4))) float float4v;

#define DEV __device__ __forceinline__

constexpr int Bsz = 4, Sseq = 2048, Dm = 1024, NHn = 16, HSn = 64;
// fold 1/sqrt(HS) * log2(e) into Wq so attention softmax runs in exp2 domain
constexpr float QSCALE = 0.125f * 1.4426950408889634f;

// ---- workspace layout (bytes) ----
constexpr size_t SZ_BF_XY = (size_t)Bsz * Sseq * Dm * 2;  // 16 MiB
constexpr size_t SZ_W     = (size_t)Dm * Dm * 2;          // 2 MiB
constexpr size_t OFF_XBF  = 0;
constexpr size_t OFF_YBF  = OFF_XBF + SZ_BF_XY;
constexpr size_t OFF_WQ   = OFF_YBF + SZ_BF_XY;
constexpr size_t OFF_WK   = OFF_WQ + SZ_W;
constexpr size_t OFF_WV   = OFF_WK + SZ_W;
constexpr size_t OFF_WP   = OFF_WV + SZ_W;
constexpr size_t OFF_QWS  = OFF_WP + SZ_W;   // [BH][S][64] bf16
constexpr size_t OFF_KWS  = OFF_QWS + SZ_BF_XY;
constexpr size_t OFF_VTWS = OFF_KWS + SZ_BF_XY; // [BH][64][S] bf16 (V transposed)
constexpr size_t OFF_OWS  = OFF_VTWS + SZ_BF_XY; // attn out [B][S][D] bf16
constexpr size_t OFF_FLAG = OFF_OWS + SZ_BF_XY;

DEV unsigned short f2bf(float f) {
  union { float f; unsigned int u; } v; v.f = f;
  unsigned int r = (v.u + 0x7FFFu + ((v.u >> 16) & 1u)) >> 16;
  return (unsigned short)r;
}

DEV void gll16(const void* g, void* l) {
  __builtin_amdgcn_global_load_lds((const __attribute__((address_space(1))) unsigned int*)g,
                                   (__attribute__((address_space(3))) unsigned int*)l, 16, 0, 0);
}

// ---------------- convert fp32 -> bf16 (x8 per thread) ----------------
__global__ void cvt_kernel(const float* __restrict__ src, unsigned short* __restrict__ dst,
                           int n8, float scale) {
  int i = blockIdx.x * blockDim.x + threadIdx.x;
  if (i >= n8) return;
  const float4v* s = (const float4v*)src + (size_t)i * 2;
  float4v a = s[0], b = s[1];
  s16x8 o;
  o[0] = (short)f2bf(a[0] * scale); o[1] = (short)f2bf(a[1] * scale);
  o[2] = (short)f2bf(a[2] * scale); o[3] = (short)f2bf(a[3] * scale);
  o[4] = (short)f2bf(b[0] * scale); o[5] = (short)f2bf(b[1] * scale);
  o[6] = (short)f2bf(b[2] * scale); o[7] = (short)f2bf(b[3] * scale);
  *(s16x8*)(dst + (size_t)i * 8) = o;
}

// ---------------- mask triviality flag ----------------
__global__ void init_flag(int* f) { f[0] = 1; }
__global__ void check_mask(const int* __restrict__ p, int n, int* __restrict__ f) {
  int bad = 0;
  for (int i = blockIdx.x * blockDim.x + threadIdx.x; i < n; i += gridDim.x * blockDim.x)
    bad |= (p[i] == 0);
  if (bad) atomicAnd(f, 0);
}

// ---------------- 128x128 bf16 GEMM, C[m][n] = sum_k A[m][k] * W[n][k] ----------------
// V=0: Q out bf16 [B,NH,S,HS]   V=1: K out, same layout
// V=2: Vt out bf16 [B,NH,HS,S] (LDS-transposed epilogue)
// V=3: fp32 out [M][1024] + bias
template <int V>
__global__ __launch_bounds__(256) void gemm_k(const unsigned short* __restrict__ A,
                                              const unsigned short* __restrict__ W,
                                              unsigned short* __restrict__ outb,
                                              float* __restrict__ outf,
                                              const float* __restrict__ bias) {
  constexpr int K = 1024;
  __shared__ unsigned short sm[17408]; // lA(4096) + lB(4096); V2 transpose uses 128*136
  unsigned short* lA = sm;
  unsigned short* lB = sm + 4096;
  const int tid = threadIdx.x;
  const int w = tid >> 6, lane = tid & 63, lo = lane & 15, hi = lane >> 4;
  const int wm = w >> 1, wn = w & 1;
  const int m0 = blockIdx.x * 128, n0 = blockIdx.y * 128;
  f32x4 acc[4][4] = {};

  for (int k0 = 0; k0 < K; k0 += 32) {
#pragma unroll
    for (int h = 0; h < 2; ++h) {
      int c = w * 64 + h * 256 + lane;
      gll16(A + (size_t)(m0 + (c >> 2)) * K + k0 + (c & 3) * 8, lA + (size_t)(w * 64 + h * 256) * 8);
      gll16(W + (size_t)(n0 + (c >> 2)) * K + k0 + (c & 3) * 8, lB + (size_t)(w * 64 + h * 256) * 8);
    }
    __syncthreads();
    s16x8 af[4], bfr[4];
#pragma unroll
    for (int mi = 0; mi < 4; ++mi) af[mi] = *(const s16x8*)&lA[(wm * 64 + mi * 16 + lo) * 32 + hi * 8];
#pragma unroll
    for (int ni = 0; ni < 4; ++ni) bfr[ni] = *(const s16x8*)&lB[(wn * 64 + ni * 16 + lo) * 32 + hi * 8];
#pragma unroll
    for (int mi = 0; mi < 4; ++mi)
#pragma unroll
      for (int ni = 0; ni < 4; ++ni)
        acc[mi][ni] = __builtin_amdgcn_mfma_f32_16x16x32_bf16(af[mi], bfr[ni], acc[mi][ni], 0, 0, 0);
    __syncthreads();
  }

  if constexpr (V <= 1) {
#pragma unroll
    for (int mi = 0; mi < 4; ++mi)
#pragma unroll
      for (int ni = 0; ni < 4; ++ni)
#pragma unroll
        for (int j = 0; j < 4; ++j) {
          int m = m0 + wm * 64 + mi * 16 + hi * 4 + j;
          int n = n0 + wn * 64 + ni * 16 + lo;
          int b = m >> 11, s = m & 2047, hh = n >> 6, e = n & 63;
          outb[((size_t)(b * NHn + hh) * Sseq + s) * HSn + e] = f2bf(acc[mi][ni][j]);
        }
  } else if constexpr (V == 2) {
    __syncthreads();
#pragma unroll
    for (int mi = 0; mi < 4; ++mi)
#pragma unroll
      for (int ni = 0; ni < 4; ++ni)
#pragma unroll
        for (int j = 0; j < 4; ++j) {
          int ml = wm * 64 + mi * 16 + hi * 4 + j;
          int nl = wn * 64 + ni * 16 + lo;
          sm[(size_t)nl * 136 + ml] = f2bf(acc[mi][ni][j]);
        }
    __syncthreads();
    int nl = tid >> 1, half = tid & 1;
    int b = m0 >> 11, hh = (n0 + nl) >> 6, e = (n0 + nl) & 63;
    unsigned short* dst = outb + ((size_t)(b * NHn + hh) * HSn + e) * Sseq + (m0 & 2047) + half * 64;
#pragma unroll
    for (int i = 0; i < 8; ++i)
      *(s16x8*)(dst + i * 8) = *(const s16x8*)&sm[(size_t)nl * 136 + half * 64 + i * 8];
  } else {
    float bv[4];
#pragma unroll
    for (int ni = 0; ni < 4; ++ni) bv[ni] = bias[n0 + wn * 64 + ni * 16 + lo];
#pragma unroll
    for (int mi = 0; mi < 4; ++mi)
#pragma unroll
      for (int ni = 0; ni < 4; ++ni)
#pragma unroll
        for (int j = 0; j < 4; ++j) {
          int m = m0 + wm * 64 + mi * 16 + hi * 4 + j;
          int n = n0 + wn * 64 + ni * 16 + lo;
          outf[(size_t)m * 1024 + n] = acc[mi][ni][j] + bv[ni];
        }
  }
}

// ---------------- flash attention ----------------
// R1-verified per-tile math, restructured for load balance:
// block (ip, bh) handles q-tiles qtA=ip and qtB=15-ip (128 rows each) ->
// every block does exactly 34 K-tile iterations (perfect balance), K/V staged
// once per pair with double-buffered issue-early/write-late register staging.
// Per wave: 32 q-rows of each q-tile. Layouts identical to R1:
// sreg[mq][t][j] = S[q=qw0+mq*16+hi*4+j][kpos=k0+t*16+lo],
// oacc[et][ql][j] = O^T[e=et*16+hi*4+j][q=ql*16+lo].
DEV void attn_tile32(const unsigned short* __restrict__ kbc,
                     const unsigned short* __restrict__ vbc,
                     const s16x8 (&qf)[2][2], f32x4 (&oacc)[4][2],
                     float (&mrun)[2][4], float (&lrun)[2][4],
                     unsigned short* __restrict__ pbw, float* __restrict__ bcw,
                     int k0, int qw0, int lo, int hi, int b,
                     const int* __restrict__ pad, const int* __restrict__ tmask,
                     bool trivial) {
  if (k0 > qw0 + 31) return; // wave-uniform: no kpos in this tile is visible to any row

  // S = Q K^T  (C-layout: row q = hi*4+j, col kpos = lo)
  f32x4 sreg[2][4];
#pragma unroll
  for (int t = 0; t < 4; ++t) {
    f32x4 s0 = {0.f, 0.f, 0.f, 0.f}, s1 = {0.f, 0.f, 0.f, 0.f};
#pragma unroll
    for (int kk = 0; kk < 2; ++kk) {
      s16x8 kfr = *(const s16x8*)&kbc[(t * 16 + lo) * 72 + kk * 32 + hi * 8];
      s0 = __builtin_amdgcn_mfma_f32_16x16x32_bf16(qf[0][kk], kfr, s0, 0, 0, 0);
      s1 = __builtin_amdgcn_mfma_f32_16x16x32_bf16(qf[1][kk], kfr, s1, 0, 0, 0);
    }
    sreg[0][t] = s0; sreg[1][t] = s1;
  }
  if (k0 + 63 > qw0) { // diagonal tiles: causal mask
#pragma unroll
    for (int mq = 0; mq < 2; ++mq)
#pragma unroll
      for (int t = 0; t < 4; ++t)
#pragma unroll
        for (int j = 0; j < 4; ++j) {
          int qg = qw0 + mq * 16 + hi * 4 + j;
          int kg = k0 + t * 16 + lo;
          if (kg > qg) sreg[mq][t][j] = -3e38f;
        }
  }
  if (!trivial) { // general pad/time masks (not hit for all-ones inputs)
#pragma unroll
    for (int t = 0; t < 4; ++t) {
      int kg = k0 + t * 16 + lo;
      int pv = pad[b * Sseq + kg];
#pragma unroll
      for (int mq = 0; mq < 2; ++mq)
#pragma unroll
        for (int j = 0; j < 4; ++j) {
          int qg = qw0 + mq * 16 + hi * 4 + j;
          if (!pv || !tmask[(size_t)qg * Sseq + kg]) sreg[mq][t][j] = -3e38f;
        }
    }
  }
  // online softmax (exp2 domain), per row (mq, j)
#pragma unroll
  for (int mq = 0; mq < 2; ++mq)
#pragma unroll
    for (int j = 0; j < 4; ++j) {
      float mx = fmaxf(fmaxf(sreg[mq][0][j], sreg[mq][1][j]),
                       fmaxf(sreg[mq][2][j], sreg[mq][3][j]));
      mx = fmaxf(mx, __shfl_xor(mx, 1, 64));
      mx = fmaxf(mx, __shfl_xor(mx, 2, 64));
      mx = fmaxf(mx, __shfl_xor(mx, 4, 64));
      mx = fmaxf(mx, __shfl_xor(mx, 8, 64));
      float mnew = fmaxf(mrun[mq][j], mx);
      float al = __builtin_amdgcn_exp2f(mrun[mq][j] - mnew);
      mrun[mq][j] = mnew;
      float rs = 0.f;
#pragma unroll
      for (int t = 0; t < 4; ++t) {
        float p = __builtin_amdgcn_exp2f(sreg[mq][t][j] - mnew);
        sreg[mq][t][j] = p;
        rs += p;
      }
      rs += __shfl_xor(rs, 1, 64);
      rs += __shfl_xor(rs, 2, 64);
      rs += __shfl_xor(rs, 4, 64);
      rs += __shfl_xor(rs, 8, 64);
      lrun[mq][j] = lrun[mq][j] * al + rs;
      if (lo == 0) bcw[mq * 16 + hi * 4 + j] = al;
    }
  // P -> LDS bf16 [q][kpos]
#pragma unroll
  for (int mq = 0; mq < 2; ++mq)
#pragma unroll
    for (int t = 0; t < 4; ++t)
#pragma unroll
      for (int j = 0; j < 4; ++j)
        pbw[(mq * 16 + hi * 4 + j) * 72 + t * 16 + lo] = f2bf(sreg[mq][t][j]);
  // rescale O^T accumulators (col = q = lo)
  float av0 = bcw[lo], av1 = bcw[16 + lo];
#pragma unroll
  for (int et = 0; et < 4; ++et) { oacc[et][0] *= av0; oacc[et][1] *= av1; }
  // O^T += V^T P^T
  s16x8 pf[2][2];
#pragma unroll
  for (int ql = 0; ql < 2; ++ql)
#pragma unroll
    for (int kk = 0; kk < 2; ++kk)
      pf[ql][kk] = *(const s16x8*)&pbw[(ql * 16 + lo) * 72 + kk * 32 + hi * 8];
#pragma unroll
  for (int et = 0; et < 4; ++et)
#pragma unroll
    for (int kk = 0; kk < 2; ++kk) {
      s16x8 vfr = *(const s16x8*)&vbc[(et * 16 + lo) * 72 + kk * 32 + hi * 8];
      oacc[et][0] = __builtin_amdgcn_mfma_f32_16x16x32_bf16(vfr, pf[0][kk], oacc[et][0], 0, 0, 0);
      oacc[et][1] = __builtin_amdgcn_mfma_f32_16x16x32_bf16(vfr, pf[1][kk], oacc[et][1], 0, 0, 0);
    }
}

// normalize by l and write O via per-wave LDS transpose (R1-verified)
DEV void attn_epilogue32(f32x4 (&oacc)[4][2], float (&lrun)[2][4],
                         unsigned short* __restrict__ pbw, float* __restrict__ bcw,
                         unsigned short* __restrict__ O, int b, int hh, int qw0,
                         int lane, int lo, int hi) {
  if (lo == 0) {
#pragma unroll
    for (int mq = 0; mq < 2; ++mq)
#pragma unroll
      for (int j = 0; j < 4; ++j) bcw[mq * 16 + hi * 4 + j] = lrun[mq][j];
  }
  float inv0 = 1.f / bcw[lo];
  float inv1 = 1.f / bcw[16 + lo];
#pragma unroll
  for (int et = 0; et < 4; ++et) { oacc[et][0] *= inv0; oacc[et][1] *= inv1; }
#pragma unroll
  for (int et = 0; et < 4; ++et)
#pragma unroll
    for (int ql = 0; ql < 2; ++ql)
#pragma unroll
      for (int j = 0; j < 4; ++j)
        pbw[(ql * 16 + lo) * 72 + et * 16 + hi * 4 + j] = f2bf(oacc[et][ql][j]);
  int q = lane & 31, half = lane >> 5;
  unsigned short* dst = O + ((size_t)b * Sseq + qw0 + q) * Dm + hh * HSn + half * 32;
#pragma unroll
  for (int i = 0; i < 4; ++i)
    *(s16x8*)(dst + i * 8) = *(const s16x8*)&pbw[q * 72 + half * 32 + i * 8];
}

__global__ __launch_bounds__(256, 2) void attn_kernel(const unsigned short* __restrict__ Q,
                                                      const unsigned short* __restrict__ Kg,
                                                      const unsigned short* __restrict__ Vt,
                                                      unsigned short* __restrict__ O,
                                                      const int* __restrict__ pad,
                                                      const int* __restrict__ tmask,
                                                      const int* __restrict__ flags) {
  __shared__ unsigned short kb[2][64 * 72];  // 18.0 KiB
  __shared__ unsigned short vb[2][64 * 72];  // 18.0 KiB
  __shared__ unsigned short pb[4][32 * 72];  // 18.0 KiB (shared A/B: same-wave reuse)
  __shared__ float bcast[4][32];

  const int ip = blockIdx.x, bh = blockIdx.y;
  const int b = bh >> 4, hh = bh & 15;
  const int tid = threadIdx.x, w = tid >> 6, lane = tid & 63, lo = lane & 15, hi = lane >> 4;
  const int qtA = ip, qtB = 15 - ip;
  const int qw0A = qtA * 128 + w * 32, qw0B = qtB * 128 + w * 32;
  const int ktA = 2 * qtA + 1;       // last K-tile index tile A needs
  const int ktmax = 2 * qtB + 2;     // number of K-tiles tile B needs
  const bool trivial = flags[0] != 0;

  const unsigned short* Qb = Q + (size_t)bh * Sseq * HSn;
  const unsigned short* Kb = Kg + (size_t)bh * Sseq * HSn;
  const unsigned short* Vb = Vt + (size_t)bh * HSn * Sseq;

  // Q fragments (A-operand: row=lo, k=hi*8+j) for both q-tiles
  s16x8 qfA[2][2], qfB[2][2];
#pragma unroll
  for (int mq = 0; mq < 2; ++mq)
#pragma unroll
    for (int kk = 0; kk < 2; ++kk) {
      qfA[mq][kk] = *(const s16x8*)&Qb[(size_t)(qw0A + mq * 16 + lo) * HSn + kk * 32 + hi * 8];
      qfB[mq][kk] = *(const s16x8*)&Qb[(size_t)(qw0B + mq * 16 + lo) * HSn + kk * 32 + hi * 8];
    }

  f32x4 oaccA[4][2] = {}, oaccB[4][2] = {};
  float mrunA[2][4], lrunA[2][4], mrunB[2][4], lrunB[2][4];
#pragma unroll
  for (int mq = 0; mq < 2; ++mq)
#pragma unroll
    for (int j = 0; j < 4; ++j) {
      mrunA[mq][j] = -3e38f; lrunA[mq][j] = 0.f;
      mrunB[mq][j] = -3e38f; lrunB[mq][j] = 0.f;
    }

  const int sr = tid >> 2, sc = (tid & 3) * 16;

  // prologue: stage kt=0 into buffer 0
  s16x8 rk0, rk1, rv0, rv1;
  {
    const unsigned short* gk = Kb + (size_t)sr * HSn + sc;
    rk0 = *(const s16x8*)gk; rk1 = *(const s16x8*)(gk + 8);
    const unsigned short* gv = Vb + (size_t)sr * Sseq + sc;
    rv0 = *(const s16x8*)gv; rv1 = *(const s16x8*)(gv + 8);
  }
  *(s16x8*)&kb[0][sr * 72 + sc] = rk0; *(s16x8*)&kb[0][sr * 72 + sc + 8] = rk1;
  *(s16x8*)&vb[0][sr * 72 + sc] = rv0; *(s16x8*)&vb[0][sr * 72 + sc + 8] = rv1;
  __syncthreads();

  for (int kt = 0; kt < ktmax; ++kt) {
    const int cur = kt & 1, k0 = kt * 64;
    const bool pre = (kt + 1 < ktmax);
    if (pre) { // issue next-tile loads early; latency hides under compute
      const int k1 = k0 + 64;
      const unsigned short* gk = Kb + (size_t)(k1 + sr) * HSn + sc;
      rk0 = *(const s16x8*)gk; rk1 = *(const s16x8*)(gk + 8);
      const unsigned short* gv = Vb + (size_t)sr * Sseq + k1 + sc;
      rv0 = *(const s16x8*)gv; rv1 = *(const s16x8*)(gv + 8);
    }
    const unsigned short* kbc = kb[cur];
    const unsigned short* vbc = vb[cur];
    if (kt <= ktA)
      attn_tile32(kbc, vbc, qfA, oaccA, mrunA, lrunA, pb[w], bcast[w],
                  k0, qw0A, lo, hi, b, pad, tmask, trivial);
    attn_tile32(kbc, vbc, qfB, oaccB, mrunB, lrunB, pb[w], bcast[w],
                k0, qw0B, lo, hi, b, pad, tmask, trivial);
    if (pre) { // write-late into the other buffer
      const int nb = cur ^ 1;
      *(s16x8*)&kb[nb][sr * 72 + sc] = rk0; *(s16x8*)&kb[nb][sr * 72 + sc + 8] = rk1;
      *(s16x8*)&vb[nb][sr * 72 + sc] = rv0; *(s16x8*)&vb[nb][sr * 72 + sc + 8] = rv1;
    }
    __syncthreads();
  }

  attn_epilogue32(oaccA, lrunA, pb[w], bcast[w], O, b, hh, qw0A - w * 32 + w * 32, lane, lo, hi);
  attn_epilogue32(oaccB, lrunB, pb[w], bcast[w], O, b, hh, qw0B, lane, lo, hi);
}

extern "C" void kernel_launch(void* const* d_in, const int* in_sizes, int n_in,
                              void* d_out, int out_size, void* d_ws, size_t ws_size,
                              hipStream_t stream) {
  const float* x = (const float*)d_in[0];
  const float* y = (const float*)d_in[1];
  const int* pad = (const int*)d_in[2];
  const int* tmask = (const int*)d_in[3];
  const float* Wq = (const float*)d_in[4];
  const float* Wk = (const float*)d_in[5];
  const float* Wv = (const float*)d_in[6];
  const float* Wp = (const float*)d_in[7];
  const float* bp = (const float*)d_in[8];

  char* ws = (char*)d_ws;
  unsigned short* xbf = (unsigned short*)(ws + OFF_XBF);
  unsigned short* ybf = (unsigned short*)(ws + OFF_YBF);
  unsigned short* wqb = (unsigned short*)(ws + OFF_WQ);
  unsigned short* wkb = (unsigned short*)(ws + OFF_WK);
  unsigned short* wvb = (unsigned short*)(ws + OFF_WV);
  unsigned short* wpb = (unsigned short*)(ws + OFF_WP);
  unsigned short* qws = (unsigned short*)(ws + OFF_QWS);
  unsigned short* kws = (unsigned short*)(ws + OFF_KWS);
  unsigned short* vtw = (unsigned short*)(ws + OFF_VTWS);
  unsigned short* ows = (unsigned short*)(ws + OFF_OWS);
  int* flags = (int*)(ws + OFF_FLAG);

  init_flag<<<1, 1, 0, stream>>>(flags);
  check_mask<<<64, 256, 0, stream>>>(pad, Bsz * Sseq, flags);
  check_mask<<<2048, 256, 0, stream>>>(tmask, Sseq * Sseq, flags);

  cvt_kernel<<<4096, 256, 0, stream>>>(x, xbf, 1048576, 1.f);
  cvt_kernel<<<4096, 256, 0, stream>>>(y, ybf, 1048576, 1.f);
  cvt_kernel<<<512, 256, 0, stream>>>(Wq, wqb, 131072, QSCALE);
  cvt_kernel<<<512, 256, 0, stream>>>(Wk, wkb, 131072, 1.f);
  cvt_kernel<<<512, 256, 0, stream>>>(Wv, wvb, 131072, 1.f);
  cvt_kernel<<<512, 256, 0, stream>>>(Wp, wpb, 131072, 1.f);

  dim3 gg(64, 8);
  gemm_k<0><<<gg, 256, 0, stream>>>(ybf, wqb, qws, nullptr, nullptr);
  gemm_k<1><<<gg, 256, 0, stream>>>(xbf, wkb, kws, nullptr, nullptr);
  gemm_k<2><<<gg, 256, 0, stream>>>(xbf, wvb, vtw, nullptr, nullptr);

  attn_kernel<<<dim3(8, 64), 256, 0, stream>>>(qws, kws, vtw, ows, pad, tmask, flags);

  gemm_k<3><<<gg, 256, 0, stream>>>(ows, wpb, nullptr, (float*)d_out, bp);
}